// Round 8
// baseline (202.182 us; speedup 1.0000x reference)
//
#include <hip/hip_runtime.h>

// LSTM_52922587021316 — Round 11: LDS diet (B0 weights -> regs, 5 blocks/CU)
// + epilogue v2.5 (pair-batched Rig/Rh, 6.5 trans/h).
// R10 calibration: removing 2.5 trans/h saved only ~235 cy/wave-t -> trans
// ~8 issue-cy, lever nearly exhausted. Waves stall ~75% of lifetime; 3.2
// waves/SIMD -> VALUBusy 76.5%. Two bounded-risk changes:
// 1) B0 (layer-0 Whh) to registers (+32 VGPR, loaded from global once; W0
//    is L2-resident). LDS 38400->29952 < 32K -> 5 blocks/CU (62.5% cap).
//    launch_bounds(256,2) keeps VGPR budget 256 -> allocator never forced
//    to spill (R7/R8 failure mode). Worst case: VGPR>102 -> still 4 blocks.
// 2) Pair-batch Rig=rcp(M0*M1), Rh=rcp(Dh0*Dh1) (products <=2^54/2^66, no
//    overflow). Sum structure of c-recurrence UNTOUCHED (R9's cancellation
//    failure was from restructuring sums, not rcp batching).

#define HID 32
#define TSTEPS 7
#define LSTRIDE 40   // halves per LDS h-row: 32 + 8 pad (80 B, 16B-aligned)
#define NWAVES 4     // waves per block

typedef _Float16 half8 __attribute__((ext_vector_type(8)));
typedef float floatx4 __attribute__((ext_vector_type(4)));
typedef float floatx2 __attribute__((ext_vector_type(2)));

#define LOG2E 1.44269504088896f

__device__ __forceinline__ float fast_rcp(float x) { return __builtin_amdgcn_rcpf(x); }

__device__ __forceinline__ float exp2_fast(float x) {
#if __has_builtin(__builtin_amdgcn_exp2f)
    return __builtin_amdgcn_exp2f(x);
#else
    return __expf(x * 0.69314718055994531f);
#endif
}

__global__ __launch_bounds__(256, 2) void lstm2_mfma(
    const float* __restrict__ xin,   // [B, 7]
    const float* __restrict__ Wih0,  // [128, 1]
    const float* __restrict__ Whh0,  // [128, 32]
    const float* __restrict__ bih0,  // [128]
    const float* __restrict__ bhh0,  // [128]
    const float* __restrict__ Wih1,  // [128, 32]
    const float* __restrict__ Whh1,  // [128, 32]
    const float* __restrict__ bih1,  // [128]
    const float* __restrict__ bhh1,  // [128]
    const float* __restrict__ fcw,   // [32]
    const float* __restrict__ fcb,   // [1]
    const float* __restrict__ fc1w,  // [7]
    const float* __restrict__ fc1b,  // [1]
    float* __restrict__ out,         // [B]
    int B)
{
    const int lane = threadIdx.x & 63;
    const int wave = threadIdx.x >> 6;
    const int col  = lane & 15;          // C col / A row m
    const int rg   = lane >> 4;          // C rows rg*4..+3 / A k-chunk rg*8..+7
    const int seq_base = (blockIdx.x * NWAVES + wave) * 16;

    // LDS weight fragments for layer-1 matrices only (B0 lives in regs):
    // matrix m in {0:Wih1, 1:Whh1}, tile nt (0..7), lane, 8 halves.
    // byte offset = m*8192 + nt*1024 + lane*16  -> ds_read_b128, conflict-free.
    __shared__ __align__(16) _Float16 ldsw[2 * 8 * 64 * 8];   // 16 KiB
    __shared__ __align__(16) floatx2  ldsbw0[128];            // {b0s, wx} by n, 1 KiB
    __shared__ float                  ldsb1[128];             // b1s by n, 0.5 KiB
    __shared__ __align__(16) _Float16 ldsh[NWAVES][2][16 * LSTRIDE];
    __shared__ __align__(16) float    ldsx[NWAVES][TSTEPS * 16];

    _Float16* h1l = &ldsh[wave][0][0];
    _Float16* h2l = &ldsh[wave][1][0];
    float* xl = &ldsx[wave][0];

    // ---- stage x: 112 contiguous floats per wave -> transposed [t][seq] ---
#pragma unroll
    for (int e = lane; e < TSTEPS * 16; e += 64) {
        const int s = e / TSTEPS;
        const int tt = e - s * TSTEPS;
        xl[tt * 16 + s] = xin[seq_base * TSTEPS + e];
    }

    // ---- B0 (prescaled Whh0) straight into registers: W0 is L2-resident --
    half8 B0r[8];
#pragma unroll
    for (int nt = 0; nt < 8; ++nt) {
        const int n = nt * 16 + col;
        const float sc = ((n >> 5) == 2) ? (2.0f * LOG2E) : (-LOG2E);
        const float* s0 = Whh0 + n * HID + rg * 8;
        const floatx4 a = *(const floatx4*)(s0);
        const floatx4 b = *(const floatx4*)(s0 + 4);
#pragma unroll
        for (int j = 0; j < 4; ++j) {
            B0r[nt][j]     = (_Float16)(sc * a[j]);
            B0r[nt][4 + j] = (_Float16)(sc * b[j]);
        }
    }

    // ---- stage prescaled layer-1 weights/biases into LDS (once/block) ----
    if (wave < 2) {
        const float* Wsrc = (wave == 0) ? Wih1 : Whh1;
#pragma unroll
        for (int nt = 0; nt < 8; ++nt) {
            const int n = nt * 16 + col;
            const float sc = ((n >> 5) == 2) ? (2.0f * LOG2E) : (-LOG2E);
            const float* s = Wsrc + n * HID + rg * 8;
            half8 f;
#pragma unroll
            for (int j = 0; j < 8; ++j) f[j] = (_Float16)(sc * s[j]);
            *(half8*)&ldsw[((wave * 8 + nt) * 64 + lane) * 8] = f;
        }
    } else if (wave == 2) {
#pragma unroll
        for (int i = 0; i < 2; ++i) {
            const int n = i * 64 + lane;
            const float sc = ((n >> 5) == 2) ? (2.0f * LOG2E) : (-LOG2E);
            floatx2 bw;
            bw[0] = sc * (bih0[n] + bhh0[n]);   // prescaled layer-0 bias
            bw[1] = sc * Wih0[n];               // prescaled rank-1 x weight
            ldsbw0[n] = bw;
            ldsb1[n]  = sc * (bih1[n] + bhh1[n]);
        }
    }
    __syncthreads();

    const float fcw_l0 = fcw[col];
    const float fcw_l1 = fcw[16 + col];

    half8 Ah1 = {};      // h1 in A-layout (zero at t=0)
    half8 Ah2 = {};      // h2 in A-layout
    float c1[2][4] = {}, c2[2][4] = {};
    float facc[4] = {0.f, 0.f, 0.f, 0.f};

    for (int t = 0; t < TSTEPS; ++t) {
        // Opaque zero offset: keeps the LDS weight loads inside the loop so
        // LICM can't hoist Wih1/Whh1 fragments back into 64 registers.
        unsigned woff = 0;
        asm volatile("" : "+v"(woff));
        const char* wB  = (const char*)ldsw   + lane * 16 + woff;
        const char* bB0 = (const char*)ldsbw0 + col * 8  + woff;
        const char* bB1 = (const char*)ldsb1  + col * 4  + woff;

        // x for my 4 C-rows (m = rg*4 + r): one b128, conflict-free broadcast
        const floatx4 xr = *(const floatx4*)&xl[t * 16 + rg * 4];

        // -------- layer 0: gates = (bias + x*Wih0) + h1_prev @ Whh0^T -----
        floatx4 g0[8];
#pragma unroll
        for (int nt = 0; nt < 8; ++nt) {
            const floatx2 bw = *(const floatx2*)(bB0 + nt * 128);
            floatx4 c;
#pragma unroll
            for (int r = 0; r < 4; ++r) c[r] = fmaf(bw[1], xr[r], bw[0]);
            g0[nt] = __builtin_amdgcn_mfma_f32_16x16x32_f16(Ah1, B0r[nt], c, 0, 0, 0);
        }

        // epilogue 0: v2.5 cell update (pair-batched Rb/Rm/Rh), write h1
#pragma unroll
        for (int q = 0; q < 2; ++q) {
#pragma unroll
            for (int rp = 0; rp < 2; ++rp) {
                float Db[2], Ed[2], Ee[2], M[2];
#pragma unroll
                for (int e = 0; e < 2; ++e) {
                    const int r = rp * 2 + e;
                    const float Ea = exp2_fast(g0[0 + q][r]);
                    Db[e] = 1.0f + exp2_fast(g0[2 + q][r]);
                    Ed[e] = exp2_fast(g0[4 + q][r]);
                    Ee[e] = exp2_fast(g0[6 + q][r]);
                    M[e]  = (1.0f + Ea) * (1.0f + Ed[e]);
                }
                const float Rb = fast_rcp(Db[0] * Db[1]);
                const float Rm = fast_rcp(M[0] * M[1]);
                float Ec[2], Dh[2];
#pragma unroll
                for (int e = 0; e < 2; ++e) {
                    const int r = rp * 2 + e;
                    const float ff  = Rb * Db[1 - e];
                    const float rig = Rm * M[1 - e];
                    const float ig  = fmaf(Ed[e], rig, -rig);
                    const float c   = fmaf(ff, c1[q][r], ig);
                    c1[q][r] = c;
                    Ec[e] = exp2_fast(c * (2.0f * LOG2E));
                    Dh[e] = (1.0f + Ee[e]) * (1.0f + Ec[e]);
                }
                const float Rh = fast_rcp(Dh[0] * Dh[1]);
#pragma unroll
                for (int e = 0; e < 2; ++e) {
                    const int r = rp * 2 + e;
                    const float th = Rh * Dh[1 - e];
                    const float h  = fmaf(Ec[e], th, -th);
                    h1l[(rg * 4 + r) * LSTRIDE + q * 16 + col] = (_Float16)h;
                }
            }
        }
        Ah1 = *(const half8*)&h1l[col * LSTRIDE + rg * 8];

        // -------- layer 1: gates = bias + h1_new @ Wih1^T + h2_prev @ Whh1^T
        floatx4 g1[8];
#pragma unroll
        for (int nt = 0; nt < 8; ++nt) {
            const float b1  = *(const float*)(bB1 + nt * 64);
            const half8 f1a = *(const half8*)(wB + nt * 1024);
            const half8 f1b = *(const half8*)(wB + 8192 + nt * 1024);
            floatx4 c = {b1, b1, b1, b1};
            c = __builtin_amdgcn_mfma_f32_16x16x32_f16(Ah1, f1a, c, 0, 0, 0);
            g1[nt] = __builtin_amdgcn_mfma_f32_16x16x32_f16(Ah2, f1b, c, 0, 0, 0);
        }

        // epilogue 1: v2.5 cell update, fc partial, write h2
        const float f1t = fc1w[t];
        const float w0 = f1t * fcw_l0;
        const float w1 = f1t * fcw_l1;
#pragma unroll
        for (int q = 0; q < 2; ++q) {
            const float wq = q ? w1 : w0;
#pragma unroll
            for (int rp = 0; rp < 2; ++rp) {
                float Db[2], Ed[2], Ee[2], M[2];
#pragma unroll
                for (int e = 0; e < 2; ++e) {
                    const int r = rp * 2 + e;
                    const float Ea = exp2_fast(g1[0 + q][r]);
                    Db[e] = 1.0f + exp2_fast(g1[2 + q][r]);
                    Ed[e] = exp2_fast(g1[4 + q][r]);
                    Ee[e] = exp2_fast(g1[6 + q][r]);
                    M[e]  = (1.0f + Ea) * (1.0f + Ed[e]);
                }
                const float Rb = fast_rcp(Db[0] * Db[1]);
                const float Rm = fast_rcp(M[0] * M[1]);
                float Ec[2], Dh[2];
#pragma unroll
                for (int e = 0; e < 2; ++e) {
                    const int r = rp * 2 + e;
                    const float ff  = Rb * Db[1 - e];
                    const float rig = Rm * M[1 - e];
                    const float ig  = fmaf(Ed[e], rig, -rig);
                    const float c   = fmaf(ff, c2[q][r], ig);
                    c2[q][r] = c;
                    Ec[e] = exp2_fast(c * (2.0f * LOG2E));
                    Dh[e] = (1.0f + Ee[e]) * (1.0f + Ec[e]);
                }
                const float Rh = fast_rcp(Dh[0] * Dh[1]);
#pragma unroll
                for (int e = 0; e < 2; ++e) {
                    const int r = rp * 2 + e;
                    const float th = Rh * Dh[1 - e];
                    const float h  = fmaf(Ec[e], th, -th);
                    facc[r] = fmaf(wq, h, facc[r]);
                    h2l[(rg * 4 + r) * LSTRIDE + q * 16 + col] = (_Float16)h;
                }
            }
        }
        Ah2 = *(const half8*)&h2l[col * LSTRIDE + rg * 8];
    }

    // ---- reduce fc partials across the 16 cols, add constant tail --------
#pragma unroll
    for (int r = 0; r < 4; ++r) {
        float v = facc[r];
        v += __shfl_xor(v, 1);
        v += __shfl_xor(v, 2);
        v += __shfl_xor(v, 4);
        v += __shfl_xor(v, 8);
        facc[r] = v;
    }
    float sum_f1 = 0.f;
#pragma unroll
    for (int t = 0; t < TSTEPS; ++t) sum_f1 += fc1w[t];
    const float tail = fcb[0] * sum_f1 + fc1b[0];

    if (col == 0) {
#pragma unroll
        for (int r = 0; r < 4; ++r)
            out[seq_base + rg * 4 + r] = facc[r] + tail;
    }
}

extern "C" void kernel_launch(void* const* d_in, const int* in_sizes, int n_in,
                              void* d_out, int out_size, void* d_ws, size_t ws_size,
                              hipStream_t stream) {
    const float* xin  = (const float*)d_in[0];
    const float* Wih0 = (const float*)d_in[1];
    const float* Whh0 = (const float*)d_in[2];
    const float* bih0 = (const float*)d_in[3];
    const float* bhh0 = (const float*)d_in[4];
    const float* Wih1 = (const float*)d_in[5];
    const float* Whh1 = (const float*)d_in[6];
    const float* bih1 = (const float*)d_in[7];
    const float* bhh1 = (const float*)d_in[8];
    const float* fcw  = (const float*)d_in[9];
    const float* fcb  = (const float*)d_in[10];
    const float* fc1w = (const float*)d_in[11];
    const float* fc1b = (const float*)d_in[12];
    float* out = (float*)d_out;

    const int B = in_sizes[0] / TSTEPS;       // [B, T, F=1]
    const int grid = B / (NWAVES * 16);       // 1 block = 4 waves = 64 sequences
    lstm2_mfma<<<grid, NWAVES * 64, 0, stream>>>(
        xin, Wih0, Whh0, bih0, bhh0, Wih1, Whh1, bih1, bhh1,
        fcw, fcb, fc1w, fc1b, out, B);
}

// Round 9
// 195.146 us; speedup vs baseline: 1.0361x; 1.0361x over previous
//
#include <hip/hip_runtime.h>

// LSTM_52922587021316 — Round 12: R10 + LDS diet via single h-buffer.
// R11 lesson: B0-to-regs pushed VGPR 60->68, crossing the 64-VGPR occupancy
// quantum (waves/SIMD halves at 64/128/256) -> occupancy FELL 40->31.5,
// dur 137->146. Any occupancy play must keep VGPR <= 64.
// This round, zero-VGPR-cost LDS trim: h1 and h2 share ONE per-wave buffer
// (program order: write h1 -> read Ah1 -> write h2 over it -> read Ah2;
// same-wave DS ops are in-order -> race-free, numerics identical) and
// LSTRIDE 40->36 (write stays 2-way/free; read col*18 mod 32 spreads all
// 16 cols -> conflict-free). LDS 38400 -> 32512 <= 32K -> 5 blocks/CU,
// 20 waves/CU (62.5% cap). Weights back in LDS (VGPR ~60), epilogue = R10's
// proven v2 (7.5 trans/h). Decisive occupancy-lever test: if occ ~50% but
// VALUBusy stays ~77, the lever is dead -> pivot to cutting VALU work.

#define HID 32
#define TSTEPS 7
#define LSTRIDE 36   // halves per LDS h-row: 32 + 4 pad (72 B)
#define NWAVES 4     // waves per block

typedef _Float16 half8 __attribute__((ext_vector_type(8)));
typedef float floatx4 __attribute__((ext_vector_type(4)));
typedef float floatx2 __attribute__((ext_vector_type(2)));

#define LOG2E 1.44269504088896f

__device__ __forceinline__ float fast_rcp(float x) { return __builtin_amdgcn_rcpf(x); }

__device__ __forceinline__ float exp2_fast(float x) {
#if __has_builtin(__builtin_amdgcn_exp2f)
    return __builtin_amdgcn_exp2f(x);
#else
    return __expf(x * 0.69314718055994531f);
#endif
}

__global__ __launch_bounds__(256, 2) void lstm2_mfma(
    const float* __restrict__ xin,   // [B, 7]
    const float* __restrict__ Wih0,  // [128, 1]
    const float* __restrict__ Whh0,  // [128, 32]
    const float* __restrict__ bih0,  // [128]
    const float* __restrict__ bhh0,  // [128]
    const float* __restrict__ Wih1,  // [128, 32]
    const float* __restrict__ Whh1,  // [128, 32]
    const float* __restrict__ bih1,  // [128]
    const float* __restrict__ bhh1,  // [128]
    const float* __restrict__ fcw,   // [32]
    const float* __restrict__ fcb,   // [1]
    const float* __restrict__ fc1w,  // [7]
    const float* __restrict__ fc1b,  // [1]
    float* __restrict__ out,         // [B]
    int B)
{
    const int lane = threadIdx.x & 63;
    const int wave = threadIdx.x >> 6;
    const int col  = lane & 15;          // C col / A row m
    const int rg   = lane >> 4;          // C rows rg*4..+3 / A k-chunk rg*8..+7
    const int seq_base = (blockIdx.x * NWAVES + wave) * 16;

    // Weight fragments, block-shared, per-lane order:
    // matrix m in {0:Whh0, 1:Wih1, 2:Whh1}, tile nt (0..7), lane, 8 halves.
    // byte offset = m*8192 + nt*1024 + lane*16  -> ds_read_b128, conflict-free.
    __shared__ __align__(16) _Float16 ldsw[3 * 8 * 64 * 8];   // 24 KiB
    __shared__ __align__(16) floatx2  ldsbw0[128];            // {b0s, wx} by n, 1 KiB
    __shared__ float                  ldsb1[128];             // b1s by n, 0.5 KiB
    __shared__ __align__(16) _Float16 ldsh[NWAVES][16 * LSTRIDE];  // ONE h-buffer/wave
    __shared__ __align__(16) float    ldsx[NWAVES][TSTEPS * 16];

    _Float16* hl = &ldsh[wave][0];   // shared by h1 and h2 (in-order DS)
    float* xl = &ldsx[wave][0];

    // ---- stage x: 112 contiguous floats per wave -> transposed [t][seq] ---
#pragma unroll
    for (int e = lane; e < TSTEPS * 16; e += 64) {
        const int s = e / TSTEPS;
        const int tt = e - s * TSTEPS;
        xl[tt * 16 + s] = xin[seq_base * TSTEPS + e];
    }

    // ---- stage prescaled weights/biases into LDS (once per block) --------
    if (wave < 3) {
        const float* Wsrc = (wave == 0) ? Whh0 : (wave == 1) ? Wih1 : Whh1;
#pragma unroll
        for (int nt = 0; nt < 8; ++nt) {
            const int n = nt * 16 + col;
            const float sc = ((n >> 5) == 2) ? (2.0f * LOG2E) : (-LOG2E);
            const float* s = Wsrc + n * HID + rg * 8;
            half8 f;
#pragma unroll
            for (int j = 0; j < 8; ++j) f[j] = (_Float16)(sc * s[j]);
            *(half8*)&ldsw[((wave * 8 + nt) * 64 + lane) * 8] = f;
        }
    } else {
#pragma unroll
        for (int i = 0; i < 2; ++i) {
            const int n = i * 64 + lane;
            const float sc = ((n >> 5) == 2) ? (2.0f * LOG2E) : (-LOG2E);
            floatx2 bw;
            bw[0] = sc * (bih0[n] + bhh0[n]);   // prescaled layer-0 bias
            bw[1] = sc * Wih0[n];               // prescaled rank-1 x weight
            ldsbw0[n] = bw;
            ldsb1[n]  = sc * (bih1[n] + bhh1[n]);
        }
    }
    __syncthreads();

    const float fcw_l0 = fcw[col];
    const float fcw_l1 = fcw[16 + col];

    half8 Ah1 = {};      // h1 in A-layout (zero at t=0)
    half8 Ah2 = {};      // h2 in A-layout
    float c1[2][4] = {}, c2[2][4] = {};
    float facc[4] = {0.f, 0.f, 0.f, 0.f};

    for (int t = 0; t < TSTEPS; ++t) {
        // Opaque zero offset: makes the LDS weight addresses loop-variant so
        // LICM cannot hoist the 24 fragment loads back into 96 registers.
        unsigned woff = 0;
        asm volatile("" : "+v"(woff));
        const char* wB  = (const char*)ldsw   + lane * 16 + woff;
        const char* bB0 = (const char*)ldsbw0 + col * 8  + woff;
        const char* bB1 = (const char*)ldsb1  + col * 4  + woff;

        // x for my 4 C-rows (m = rg*4 + r): one b128, conflict-free broadcast
        const floatx4 xr = *(const floatx4*)&xl[t * 16 + rg * 4];

        // -------- layer 0: gates = (bias + x*Wih0) + h1_prev @ Whh0^T -----
        floatx4 g0[8];
#pragma unroll
        for (int nt = 0; nt < 8; ++nt) {
            const floatx2 bw = *(const floatx2*)(bB0 + nt * 128);
            const half8 bf   = *(const half8*)(wB + nt * 1024);
            floatx4 c;
#pragma unroll
            for (int r = 0; r < 4; ++r) c[r] = fmaf(bw[1], xr[r], bw[0]);
            g0[nt] = __builtin_amdgcn_mfma_f32_16x16x32_f16(Ah1, bf, c, 0, 0, 0);
        }

        // epilogue 0: v2 cell update (merged-rcp, per-element c path),
        // write h1_new to the shared h-buffer
#pragma unroll
        for (int q = 0; q < 2; ++q) {
#pragma unroll
            for (int rp = 0; rp < 2; ++rp) {
                float Ea[2], Db[2], Ed[2], Ee[2];
#pragma unroll
                for (int e = 0; e < 2; ++e) {
                    const int r = rp * 2 + e;
                    Ea[e] = exp2_fast(g0[0 + q][r]);
                    Db[e] = 1.0f + exp2_fast(g0[2 + q][r]);
                    Ed[e] = exp2_fast(g0[4 + q][r]);
                    Ee[e] = exp2_fast(g0[6 + q][r]);
                }
                const float Rb = fast_rcp(Db[0] * Db[1]);
#pragma unroll
                for (int e = 0; e < 2; ++e) {
                    const int r = rp * 2 + e;
                    const float ff  = Rb * Db[1 - e];
                    const float Rig = fast_rcp((1.0f + Ea[e]) * (1.0f + Ed[e]));
                    const float ig  = fmaf(Ed[e], Rig, -Rig);
                    const float c   = fmaf(ff, c1[q][r], ig);
                    c1[q][r] = c;
                    const float Ec  = exp2_fast(c * (2.0f * LOG2E));
                    const float Rh  = fast_rcp((1.0f + Ee[e]) * (1.0f + Ec));
                    const float h   = fmaf(Ec, Rh, -Rh);
                    hl[(rg * 4 + r) * LSTRIDE + q * 16 + col] = (_Float16)h;
                }
            }
        }
        Ah1 = *(const half8*)&hl[col * LSTRIDE + rg * 8];

        // -------- layer 1: gates = bias + h1_new @ Wih1^T + h2_prev @ Whh1^T
        floatx4 g1[8];
#pragma unroll
        for (int nt = 0; nt < 8; ++nt) {
            const float b1  = *(const float*)(bB1 + nt * 64);
            const half8 f1a = *(const half8*)(wB + 8192  + nt * 1024);
            const half8 f1b = *(const half8*)(wB + 16384 + nt * 1024);
            floatx4 c = {b1, b1, b1, b1};
            c = __builtin_amdgcn_mfma_f32_16x16x32_f16(Ah1, f1a, c, 0, 0, 0);
            g1[nt] = __builtin_amdgcn_mfma_f32_16x16x32_f16(Ah2, f1b, c, 0, 0, 0);
        }

        // epilogue 1: v2 cell update, fc partial, write h2_new over h1
        // (Ah1 already consumed; same-wave DS in-order makes this safe)
        const float f1t = fc1w[t];
        const float w0 = f1t * fcw_l0;
        const float w1 = f1t * fcw_l1;
#pragma unroll
        for (int q = 0; q < 2; ++q) {
            const float wq = q ? w1 : w0;
#pragma unroll
            for (int rp = 0; rp < 2; ++rp) {
                float Ea[2], Db[2], Ed[2], Ee[2];
#pragma unroll
                for (int e = 0; e < 2; ++e) {
                    const int r = rp * 2 + e;
                    Ea[e] = exp2_fast(g1[0 + q][r]);
                    Db[e] = 1.0f + exp2_fast(g1[2 + q][r]);
                    Ed[e] = exp2_fast(g1[4 + q][r]);
                    Ee[e] = exp2_fast(g1[6 + q][r]);
                }
                const float Rb = fast_rcp(Db[0] * Db[1]);
#pragma unroll
                for (int e = 0; e < 2; ++e) {
                    const int r = rp * 2 + e;
                    const float ff  = Rb * Db[1 - e];
                    const float Rig = fast_rcp((1.0f + Ea[e]) * (1.0f + Ed[e]));
                    const float ig  = fmaf(Ed[e], Rig, -Rig);
                    const float c   = fmaf(ff, c2[q][r], ig);
                    c2[q][r] = c;
                    const float Ec  = exp2_fast(c * (2.0f * LOG2E));
                    const float Rh  = fast_rcp((1.0f + Ee[e]) * (1.0f + Ec));
                    const float h   = fmaf(Ec, Rh, -Rh);
                    facc[r] = fmaf(wq, h, facc[r]);
                    hl[(rg * 4 + r) * LSTRIDE + q * 16 + col] = (_Float16)h;
                }
            }
        }
        Ah2 = *(const half8*)&hl[col * LSTRIDE + rg * 8];
    }

    // ---- reduce fc partials across the 16 cols, add constant tail --------
#pragma unroll
    for (int r = 0; r < 4; ++r) {
        float v = facc[r];
        v += __shfl_xor(v, 1);
        v += __shfl_xor(v, 2);
        v += __shfl_xor(v, 4);
        v += __shfl_xor(v, 8);
        facc[r] = v;
    }
    float sum_f1 = 0.f;
#pragma unroll
    for (int t = 0; t < TSTEPS; ++t) sum_f1 += fc1w[t];
    const float tail = fcb[0] * sum_f1 + fc1b[0];

    if (col == 0) {
#pragma unroll
        for (int r = 0; r < 4; ++r)
            out[seq_base + rg * 4 + r] = facc[r] + tail;
    }
}

extern "C" void kernel_launch(void* const* d_in, const int* in_sizes, int n_in,
                              void* d_out, int out_size, void* d_ws, size_t ws_size,
                              hipStream_t stream) {
    const float* xin  = (const float*)d_in[0];
    const float* Wih0 = (const float*)d_in[1];
    const float* Whh0 = (const float*)d_in[2];
    const float* bih0 = (const float*)d_in[3];
    const float* bhh0 = (const float*)d_in[4];
    const float* Wih1 = (const float*)d_in[5];
    const float* Whh1 = (const float*)d_in[6];
    const float* bih1 = (const float*)d_in[7];
    const float* bhh1 = (const float*)d_in[8];
    const float* fcw  = (const float*)d_in[9];
    const float* fcb  = (const float*)d_in[10];
    const float* fc1w = (const float*)d_in[11];
    const float* fc1b = (const float*)d_in[12];
    float* out = (float*)d_out;

    const int B = in_sizes[0] / TSTEPS;       // [B, T, F=1]
    const int grid = B / (NWAVES * 16);       // 1 block = 4 waves = 64 sequences
    lstm2_mfma<<<grid, NWAVES * 64, 0, stream>>>(
        xin, Wih0, Whh0, bih0, bhh0, Wih1, Whh1, bih1, bhh1,
        fcw, fcb, fc1w, fc1b, out, B);
}

// Round 10
// 190.579 us; speedup vs baseline: 1.0609x; 1.0240x over previous
//
#include <hip/hip_runtime.h>

// LSTM_52922587021316 — Round 13: packed-FP32 epilogue (v_pk_fma_f32 et al).
// Cross-round invariant: VALUBusy*dur ≈ 103-105us for R10/R11/R12 — total
// VALU issue time is the conserved bottleneck. Occupancy lever dead (R6,
// R12: moving occ 40<->54% leaves dur flat; R12's 5th block never resident
// — 5x32768 exact-fit refused). rcp-merge lever exhausted (v2.5 left the
// 105us untouched). Remaining fat: ~220 full-rate VALU instr/lane-t that
// gfx950 can issue 2-wide via packed fp32 (v_pk_fma_f32/_mul/_add, CDNA4
// keeps CDNA3 packed-math). This round: epilogue rewritten on float2 pairs
// (identical ops/order per element -> absmax bit-identical), v2.5 rcp
// batching (numerics proven in R11), packed accum-init and fc-accumulate.
// Shell = R12 exactly (VGPR 52 -> headroom to 64; LDS 32768, 4 blocks/CU).
// Predict dur ~118-128, VALU-time ~83-92us. Tripwire: VGPR>64.

#define HID 32
#define TSTEPS 7
#define LSTRIDE 36   // halves per LDS h-row: 32 + 4 pad (72 B)
#define NWAVES 4     // waves per block

typedef _Float16 half8 __attribute__((ext_vector_type(8)));
typedef float floatx4 __attribute__((ext_vector_type(4)));
typedef float floatx2 __attribute__((ext_vector_type(2)));

#define LOG2E 1.44269504088896f

__device__ __forceinline__ float fast_rcp(float x) { return __builtin_amdgcn_rcpf(x); }

__device__ __forceinline__ float exp2_fast(float x) {
#if __has_builtin(__builtin_amdgcn_exp2f)
    return __builtin_amdgcn_exp2f(x);
#else
    return __expf(x * 0.69314718055994531f);
#endif
}

__device__ __forceinline__ floatx2 mk2(float a, float b) {
    floatx2 v; v[0] = a; v[1] = b; return v;
}
__device__ __forceinline__ floatx2 exp2_v2(floatx2 a) {
    return mk2(exp2_fast(a[0]), exp2_fast(a[1]));
}

// v2.5 cell update on an h-pair. Scalar-identical op order to R11 (proven
// absmax 9.77e-4): Rb/Rm/Rh pair-batched, c-recurrence sum structure kept.
// All full-rate arithmetic is <2 x float> -> v_pk_* on gfx950.
__device__ __forceinline__ floatx2 cell_pair(floatx2 gi, floatx2 gf,
                                             floatx2 gg, floatx2 go,
                                             floatx2& cst) {
    const floatx2 one = mk2(1.0f, 1.0f);
    const floatx2 Ea = exp2_v2(gi);
    const floatx2 Db = exp2_v2(gf) + one;
    const floatx2 Ed = exp2_v2(gg);
    const floatx2 Ee = exp2_v2(go);
    const floatx2 M  = (Ea + one) * (Ed + one);
    const float Rb = fast_rcp(Db[0] * Db[1]);
    const float Rm = fast_rcp(M[0] * M[1]);
    const floatx2 ff  = mk2(Rb, Rb) * mk2(Db[1], Db[0]);
    const floatx2 rig = mk2(Rm, Rm) * mk2(M[1], M[0]);
    const floatx2 ig  = __builtin_elementwise_fma(Ed, rig, -rig);
    const floatx2 c   = __builtin_elementwise_fma(ff, cst, ig);
    cst = c;
    const floatx2 Ec  = exp2_v2(c * mk2(2.0f * LOG2E, 2.0f * LOG2E));
    const floatx2 Dh  = (Ee + one) * (Ec + one);
    const float Rh = fast_rcp(Dh[0] * Dh[1]);
    const floatx2 th = mk2(Rh, Rh) * mk2(Dh[1], Dh[0]);
    return __builtin_elementwise_fma(Ec, th, -th);
}

__global__ __launch_bounds__(256, 2) void lstm2_mfma(
    const float* __restrict__ xin,   // [B, 7]
    const float* __restrict__ Wih0,  // [128, 1]
    const float* __restrict__ Whh0,  // [128, 32]
    const float* __restrict__ bih0,  // [128]
    const float* __restrict__ bhh0,  // [128]
    const float* __restrict__ Wih1,  // [128, 32]
    const float* __restrict__ Whh1,  // [128, 32]
    const float* __restrict__ bih1,  // [128]
    const float* __restrict__ bhh1,  // [128]
    const float* __restrict__ fcw,   // [32]
    const float* __restrict__ fcb,   // [1]
    const float* __restrict__ fc1w,  // [7]
    const float* __restrict__ fc1b,  // [1]
    float* __restrict__ out,         // [B]
    int B)
{
    const int lane = threadIdx.x & 63;
    const int wave = threadIdx.x >> 6;
    const int col  = lane & 15;          // C col / A row m
    const int rg   = lane >> 4;          // C rows rg*4..+3 / A k-chunk rg*8..+7
    const int seq_base = (blockIdx.x * NWAVES + wave) * 16;

    // Weight fragments, block-shared, per-lane order:
    // matrix m in {0:Whh0, 1:Wih1, 2:Whh1}, tile nt (0..7), lane, 8 halves.
    // byte offset = m*8192 + nt*1024 + lane*16  -> ds_read_b128, conflict-free.
    __shared__ __align__(16) _Float16 ldsw[3 * 8 * 64 * 8];   // 24 KiB
    __shared__ __align__(16) floatx2  ldsbw0[128];            // {b0s, wx} by n, 1 KiB
    __shared__ float                  ldsb1[128];             // b1s by n, 0.5 KiB
    __shared__ __align__(16) _Float16 ldsh[NWAVES][16 * LSTRIDE];  // ONE h-buffer/wave
    __shared__ __align__(16) float    ldsx[NWAVES][TSTEPS * 16];

    _Float16* hl = &ldsh[wave][0];   // shared by h1 and h2 (same-wave DS in-order)
    float* xl = &ldsx[wave][0];

    // ---- stage x: 112 contiguous floats per wave -> transposed [t][seq] ---
#pragma unroll
    for (int e = lane; e < TSTEPS * 16; e += 64) {
        const int s = e / TSTEPS;
        const int tt = e - s * TSTEPS;
        xl[tt * 16 + s] = xin[seq_base * TSTEPS + e];
    }

    // ---- stage prescaled weights/biases into LDS (once per block) --------
    if (wave < 3) {
        const float* Wsrc = (wave == 0) ? Whh0 : (wave == 1) ? Wih1 : Whh1;
#pragma unroll
        for (int nt = 0; nt < 8; ++nt) {
            const int n = nt * 16 + col;
            const float sc = ((n >> 5) == 2) ? (2.0f * LOG2E) : (-LOG2E);
            const float* s = Wsrc + n * HID + rg * 8;
            half8 f;
#pragma unroll
            for (int j = 0; j < 8; ++j) f[j] = (_Float16)(sc * s[j]);
            *(half8*)&ldsw[((wave * 8 + nt) * 64 + lane) * 8] = f;
        }
    } else {
#pragma unroll
        for (int i = 0; i < 2; ++i) {
            const int n = i * 64 + lane;
            const float sc = ((n >> 5) == 2) ? (2.0f * LOG2E) : (-LOG2E);
            floatx2 bw;
            bw[0] = sc * (bih0[n] + bhh0[n]);   // prescaled layer-0 bias
            bw[1] = sc * Wih0[n];               // prescaled rank-1 x weight
            ldsbw0[n] = bw;
            ldsb1[n]  = sc * (bih1[n] + bhh1[n]);
        }
    }
    __syncthreads();

    const float fcw_l0 = fcw[col];
    const float fcw_l1 = fcw[16 + col];

    half8 Ah1 = {};      // h1 in A-layout (zero at t=0)
    half8 Ah2 = {};      // h2 in A-layout
    floatx2 c1v[2][2] = {}, c2v[2][2] = {};   // cell states as pk pairs
    floatx2 faccv[2] = {};                     // fc partials as pk pairs

    for (int t = 0; t < TSTEPS; ++t) {
        // Opaque zero offset: makes the LDS weight addresses loop-variant so
        // LICM cannot hoist the 24 fragment loads back into 96 registers.
        unsigned woff = 0;
        asm volatile("" : "+v"(woff));
        const char* wB  = (const char*)ldsw   + lane * 16 + woff;
        const char* bB0 = (const char*)ldsbw0 + col * 8  + woff;
        const char* bB1 = (const char*)ldsb1  + col * 4  + woff;

        // x for my 4 C-rows (m = rg*4 + r): one b128, conflict-free broadcast
        const floatx4 xr = *(const floatx4*)&xl[t * 16 + rg * 4];

        // -------- layer 0: gates = (bias + x*Wih0) + h1_prev @ Whh0^T -----
        floatx4 g0[8];
#pragma unroll
        for (int nt = 0; nt < 8; ++nt) {
            const floatx2 bw = *(const floatx2*)(bB0 + nt * 128);
            const half8 bf   = *(const half8*)(wB + nt * 1024);
            const floatx2 wv = mk2(bw[1], bw[1]);
            const floatx2 bv = mk2(bw[0], bw[0]);
            const floatx2 clo = __builtin_elementwise_fma(wv, mk2(xr[0], xr[1]), bv);
            const floatx2 chi = __builtin_elementwise_fma(wv, mk2(xr[2], xr[3]), bv);
            floatx4 c;
            c[0] = clo[0]; c[1] = clo[1]; c[2] = chi[0]; c[3] = chi[1];
            g0[nt] = __builtin_amdgcn_mfma_f32_16x16x32_f16(Ah1, bf, c, 0, 0, 0);
        }

        // epilogue 0: packed v2.5 cell update, write h1_new
#pragma unroll
        for (int q = 0; q < 2; ++q) {
#pragma unroll
            for (int rp = 0; rp < 2; ++rp) {
                const floatx2 h = cell_pair(
                    mk2(g0[0 + q][rp * 2], g0[0 + q][rp * 2 + 1]),
                    mk2(g0[2 + q][rp * 2], g0[2 + q][rp * 2 + 1]),
                    mk2(g0[4 + q][rp * 2], g0[4 + q][rp * 2 + 1]),
                    mk2(g0[6 + q][rp * 2], g0[6 + q][rp * 2 + 1]),
                    c1v[q][rp]);
                hl[(rg * 4 + rp * 2 + 0) * LSTRIDE + q * 16 + col] = (_Float16)h[0];
                hl[(rg * 4 + rp * 2 + 1) * LSTRIDE + q * 16 + col] = (_Float16)h[1];
            }
        }
        Ah1 = *(const half8*)&hl[col * LSTRIDE + rg * 8];

        // -------- layer 1: gates = bias + h1_new @ Wih1^T + h2_prev @ Whh1^T
        floatx4 g1[8];
#pragma unroll
        for (int nt = 0; nt < 8; ++nt) {
            const float b1  = *(const float*)(bB1 + nt * 64);
            const half8 f1a = *(const half8*)(wB + 8192  + nt * 1024);
            const half8 f1b = *(const half8*)(wB + 16384 + nt * 1024);
            floatx4 c = {b1, b1, b1, b1};
            c = __builtin_amdgcn_mfma_f32_16x16x32_f16(Ah1, f1a, c, 0, 0, 0);
            g1[nt] = __builtin_amdgcn_mfma_f32_16x16x32_f16(Ah2, f1b, c, 0, 0, 0);
        }

        // epilogue 1: packed v2.5 cell update, fc partial, write h2 over h1
        // (Ah1 already consumed; same-wave DS in-order makes this safe)
        const float f1t = fc1w[t];
        const float w0 = f1t * fcw_l0;
        const float w1 = f1t * fcw_l1;
#pragma unroll
        for (int q = 0; q < 2; ++q) {
            const float wq = q ? w1 : w0;
            const floatx2 wqv = mk2(wq, wq);
#pragma unroll
            for (int rp = 0; rp < 2; ++rp) {
                const floatx2 h = cell_pair(
                    mk2(g1[0 + q][rp * 2], g1[0 + q][rp * 2 + 1]),
                    mk2(g1[2 + q][rp * 2], g1[2 + q][rp * 2 + 1]),
                    mk2(g1[4 + q][rp * 2], g1[4 + q][rp * 2 + 1]),
                    mk2(g1[6 + q][rp * 2], g1[6 + q][rp * 2 + 1]),
                    c2v[q][rp]);
                faccv[rp] = __builtin_elementwise_fma(wqv, h, faccv[rp]);
                hl[(rg * 4 + rp * 2 + 0) * LSTRIDE + q * 16 + col] = (_Float16)h[0];
                hl[(rg * 4 + rp * 2 + 1) * LSTRIDE + q * 16 + col] = (_Float16)h[1];
            }
        }
        Ah2 = *(const half8*)&hl[col * LSTRIDE + rg * 8];
    }

    // ---- reduce fc partials across the 16 cols, add constant tail --------
    float facc[4];
#pragma unroll
    for (int r = 0; r < 4; ++r) facc[r] = faccv[r >> 1][r & 1];
#pragma unroll
    for (int r = 0; r < 4; ++r) {
        float v = facc[r];
        v += __shfl_xor(v, 1);
        v += __shfl_xor(v, 2);
        v += __shfl_xor(v, 4);
        v += __shfl_xor(v, 8);
        facc[r] = v;
    }
    float sum_f1 = 0.f;
#pragma unroll
    for (int t = 0; t < TSTEPS; ++t) sum_f1 += fc1w[t];
    const float tail = fcb[0] * sum_f1 + fc1b[0];

    if (col == 0) {
#pragma unroll
        for (int r = 0; r < 4; ++r)
            out[seq_base + rg * 4 + r] = facc[r] + tail;
    }
}

extern "C" void kernel_launch(void* const* d_in, const int* in_sizes, int n_in,
                              void* d_out, int out_size, void* d_ws, size_t ws_size,
                              hipStream_t stream) {
    const float* xin  = (const float*)d_in[0];
    const float* Wih0 = (const float*)d_in[1];
    const float* Whh0 = (const float*)d_in[2];
    const float* bih0 = (const float*)d_in[3];
    const float* bhh0 = (const float*)d_in[4];
    const float* Wih1 = (const float*)d_in[5];
    const float* Whh1 = (const float*)d_in[6];
    const float* bih1 = (const float*)d_in[7];
    const float* bhh1 = (const float*)d_in[8];
    const float* fcw  = (const float*)d_in[9];
    const float* fcb  = (const float*)d_in[10];
    const float* fc1w = (const float*)d_in[11];
    const float* fc1b = (const float*)d_in[12];
    float* out = (float*)d_out;

    const int B = in_sizes[0] / TSTEPS;       // [B, T, F=1]
    const int grid = B / (NWAVES * 16);       // 1 block = 4 waves = 64 sequences
    lstm2_mfma<<<grid, NWAVES * 64, 0, stream>>>(
        xin, Wih0, Whh0, bih0, bhh0, Wih1, Whh1, bih1, bhh1,
        fcw, fcb, fc1w, fc1b, out, B);
}